// Round 14
// baseline (695.931 us; speedup 1.0000x reference)
//
#include <hip/hip_runtime.h>
#include <hip/hip_bf16.h>
#include <cstdint>
#include <cstddef>

#define DEVFN __device__ __forceinline__

typedef __attribute__((ext_vector_type(4))) float f32x4;
typedef __attribute__((ext_vector_type(8))) short bf16x8;
typedef __attribute__((ext_vector_type(4))) short short4v;
typedef __attribute__((ext_vector_type(8))) short short8v;

static constexpr int S = 4096;
static constexpr int H = 3584;
static constexpr int NQ = 16;
static constexpr int NKV = 8;
static constexpr int D = 256;
static constexpr int WINDOW = 2048;
static constexpr float SCALE = 0.0625f;  // 256^-0.5

DEVFN unsigned short f2bf(float f) {
  union { float f; uint32_t u; } x; x.f = f;
  uint32_t u = x.u;
  u += 0x7fffu + ((u >> 16) & 1u);   // RNE
  return (unsigned short)(u >> 16);
}
DEVFN float bf2f(unsigned short h) {
  union { uint32_t u; float f; } x; x.u = ((uint32_t)h) << 16;
  return x.f;
}

DEVFN void load_lds16(const void* g, void* l) {
  __builtin_amdgcn_global_load_lds((const __attribute__((address_space(1))) void*)g,
                                   (__attribute__((address_space(3))) void*)l,
                                   16, 0, 0);
}

// ---------------- elementwise cast: hs f32 -> bf16 (8 elems/thread) ----------------
__global__ __launch_bounds__(256) void cast_hs_kernel(const float* __restrict__ in,
                                                      unsigned short* __restrict__ out) {
  int i = (blockIdx.x * 256 + threadIdx.x) * 8;
  float4 a = *(const float4*)(in + i);
  float4 b = *(const float4*)(in + i + 4);
  short8v o;
  o[0] = (short)f2bf(a.x); o[1] = (short)f2bf(a.y);
  o[2] = (short)f2bf(a.z); o[3] = (short)f2bf(a.w);
  o[4] = (short)f2bf(b.x); o[5] = (short)f2bf(b.y);
  o[6] = (short)f2bf(b.z); o[7] = (short)f2bf(b.w);
  *(short8v*)(out + i) = o;
}

// ---------------- transpose + cast: w[K][N] f32 -> wT[N][K] bf16, 64x64 tiles ----------------
__global__ __launch_bounds__(256) void transpose_cast_kernel(const float* __restrict__ in,
                                                             unsigned short* __restrict__ out,
                                                             int rows, int cols, int out_ld) {
  __shared__ float tile[64][65];
  const int r0 = blockIdx.y * 64, c0 = blockIdx.x * 64;
  const int t = threadIdx.x;
  const int rr = t >> 4, c4 = (t & 15) * 4;
#pragma unroll
  for (int j = 0; j < 4; ++j) {
    float4 v = *(const float4*)(in + (size_t)(r0 + rr + j * 16) * cols + c0 + c4);
    tile[rr + j * 16][c4 + 0] = v.x;
    tile[rr + j * 16][c4 + 1] = v.y;
    tile[rr + j * 16][c4 + 2] = v.z;
    tile[rr + j * 16][c4 + 3] = v.w;
  }
  __syncthreads();
  const int c = t >> 2, ch = (t & 3) * 16;
  short8v o0, o1;
#pragma unroll
  for (int j = 0; j < 8; ++j) o0[j] = (short)f2bf(tile[ch + j][c]);
#pragma unroll
  for (int j = 0; j < 8; ++j) o1[j] = (short)f2bf(tile[ch + 8 + j][c]);
  unsigned short* dst = out + (size_t)(c0 + c) * out_ld + r0 + ch;
  *(short8v*)dst = o0;
  *(short8v*)(dst + 8) = o1;
}

// ---------------- RoPE cos/sin table [S][128] x2 f32 ----------------
__global__ __launch_bounds__(256) void rope_table_kernel(float* __restrict__ cs) {
  int idx = blockIdx.x * 256 + threadIdx.x;  // S*128
  int s = idx >> 7, i = idx & 127;
  float inv = exp2f((float)i * -0.10381025296523007f);  // 10000^(-i/128)
  float f = (float)s * inv;
  cs[idx] = cosf(f);
  cs[(S * 128) + idx] = sinf(f);
}

// ---------------- RoPE apply in-place on K ONLY (bf16), 4 elems/thread ----------------
__global__ __launch_bounds__(256) void rope_apply_k_kernel(unsigned short* __restrict__ k,
                                                           const float* __restrict__ cs) {
  int idx = blockIdx.x * 256 + threadIdx.x;   // NKV*S*32
  int i4 = (idx & 31) * 4;
  int s = (idx >> 5) & (S - 1);
  int hh = idx >> 17;                          // 0..7
  unsigned short* base = k + ((size_t)hh * S + s) * D;
  float4 c  = *(const float4*)(cs + (s << 7) + i4);
  float4 sn = *(const float4*)(cs + (S * 128) + (s << 7) + i4);
  short4v a = *(short4v*)(base + i4);
  short4v b = *(short4v*)(base + i4 + 128);
  short4v o1, o2;
  o1[0] = (short)f2bf(bf2f((unsigned short)a[0]) * c.x - bf2f((unsigned short)b[0]) * sn.x);
  o1[1] = (short)f2bf(bf2f((unsigned short)a[1]) * c.y - bf2f((unsigned short)b[1]) * sn.y);
  o1[2] = (short)f2bf(bf2f((unsigned short)a[2]) * c.z - bf2f((unsigned short)b[2]) * sn.z);
  o1[3] = (short)f2bf(bf2f((unsigned short)a[3]) * c.w - bf2f((unsigned short)b[3]) * sn.w);
  o2[0] = (short)f2bf(bf2f((unsigned short)b[0]) * c.x + bf2f((unsigned short)a[0]) * sn.x);
  o2[1] = (short)f2bf(bf2f((unsigned short)b[1]) * c.y + bf2f((unsigned short)a[1]) * sn.y);
  o2[2] = (short)f2bf(bf2f((unsigned short)b[2]) * c.z + bf2f((unsigned short)a[2]) * sn.z);
  o2[3] = (short)f2bf(bf2f((unsigned short)b[3]) * c.w + bf2f((unsigned short)a[3]) * sn.w);
  *(short4v*)(base + i4) = o1;
  *(short4v*)(base + i4 + 128) = o2;
}

// ================== 256x256 8-phase GEMM (T2+T3+T4+T5) ==================
DEVFN void gemm256_mainloop(const unsigned short* __restrict__ A,
                            const unsigned short* __restrict__ Bt,
                            int Kdim, int lda, int ldb, int row0, int col0,
                            char* lds, f32x4 acc[8][4]) {
  const int tid = threadIdx.x, lane = tid & 63;
  const int w = tid >> 6;
  const int wm = w >> 2, wn = w & 3;
  const int NT = Kdim >> 6;

  const int u = ((tid & 7) * 16) ^ (((tid >> 3) & 7) << 4);
  const int srow = (tid >> 3) + (u >> 6) * 128;
  const int sc = (u & 63) >> 1;

  const unsigned short* aSrc = A + (size_t)(row0 + srow) * lda + sc;
  const unsigned short* bSrc = Bt + (size_t)(col0 + srow) * ldb + sc;
  const size_t aj = (size_t)64 * lda, bj = (size_t)64 * ldb;

  char* const dA = lds + tid * 16;
  char* const dB = lds + 32768 + tid * 16;

  const int aoff = (lane & 15) * 128 + ((((lane >> 4) * 16) + wm * 64) ^ ((lane & 7) << 4));
  const int boff = ((wn & 1) * 64 + (lane & 15)) * 128 +
                   ((((lane >> 4) * 16) + (wn >> 1) * 64) ^ ((lane & 7) << 4));

#define STAGE_A(kt2, kh) do { \
    char* d_ = dA + (((kt2) & 1) << 16) + ((kh) << 14); \
    const unsigned short* s_ = aSrc + (kt2) * 64 + (kh) * 32; \
    load_lds16(s_, d_); load_lds16(s_ + aj, d_ + 8192); } while (0)
#define STAGE_B(kt2, kh) do { \
    char* d_ = dB + (((kt2) & 1) << 16) + ((kh) << 14); \
    const unsigned short* s_ = bSrc + (kt2) * 64 + (kh) * 32; \
    load_lds16(s_, d_); load_lds16(s_ + bj, d_ + 8192); } while (0)

  STAGE_A(0, 0); STAGE_B(0, 0); STAGE_A(0, 1); STAGE_B(0, 1);
  if (NT > 1) { STAGE_A(1, 0); STAGE_B(1, 0); }
  asm volatile("s_waitcnt vmcnt(4)" ::: "memory");
  __builtin_amdgcn_s_barrier();
  asm volatile("" ::: "memory");

  for (int kt = 0; kt < NT; ++kt) {
    const char* lA = lds + ((kt & 1) << 16) + aoff;
    const char* lB = lds + ((kt & 1) << 16) + 32768 + boff;
    bf16x8 bfr[4];
#pragma unroll
    for (int ph = 0; ph < 4; ++ph) {
      const int kh = ph >> 1;
      const int mh = ph & 1;
      bf16x8 af[4];
#pragma unroll
      for (int j = 0; j < 4; ++j)
        af[j] = *(const bf16x8*)(lA + (kh << 14) + (mh * 4 + j) * 2048);
      if (mh == 0) {
#pragma unroll
        for (int n = 0; n < 4; ++n)
          bfr[n] = *(const bf16x8*)(lB + (kh << 14) + n * 2048);
      }
      if (ph == 0)      { if (kt + 1 < NT) STAGE_A(kt + 1, 1); }
      else if (ph == 1) { if (kt + 1 < NT) STAGE_B(kt + 1, 1); }
      else if (ph == 2) { if (kt + 2 < NT) STAGE_A(kt + 2, 0); }
      else              { if (kt + 2 < NT) STAGE_B(kt + 2, 0); }

      asm volatile("" ::: "memory");
      __builtin_amdgcn_s_barrier();
      asm volatile("" ::: "memory");
      __builtin_amdgcn_s_setprio(1);
#pragma unroll
      for (int j = 0; j < 4; ++j)
#pragma unroll
        for (int n = 0; n < 4; ++n)
          acc[mh * 4 + j][n] =
              __builtin_amdgcn_mfma_f32_16x16x32_bf16(af[j], bfr[n], acc[mh * 4 + j][n], 0, 0, 0);
      __builtin_amdgcn_s_setprio(0);
      if (ph == 3) {
        if (kt < NT - 2) asm volatile("s_waitcnt vmcnt(4)" ::: "memory");
        else             asm volatile("s_waitcnt vmcnt(0)" ::: "memory");
      }
      asm volatile("" ::: "memory");
      __builtin_amdgcn_s_barrier();
      asm volatile("" ::: "memory");
    }
  }
#undef STAGE_A
#undef STAGE_B
}

// ---------------- GEMM 1: [S][H] x [H][8192] -> scatter to q, k, vt ----------------
__global__ __launch_bounds__(512, 2) void gemm_qkv_kernel(const unsigned short* __restrict__ A,
                                                          const unsigned short* __restrict__ Bt,
                                                          unsigned short* __restrict__ qb,
                                                          unsigned short* __restrict__ kbuf,
                                                          unsigned short* __restrict__ vtb) {
  extern __shared__ char lds[];
  int bid = blockIdx.x;                 // 512 blocks
  bid = (bid & 7) * 64 + (bid >> 3);    // bijective XCD swizzle
  const int bx = bid & 15, by = bid >> 4;
  const int row0 = bx * 256, col0 = by * 256;
  f32x4 acc[8][4];
  f32x4 z = {0.f, 0.f, 0.f, 0.f};
#pragma unroll
  for (int m = 0; m < 8; ++m)
#pragma unroll
    for (int n = 0; n < 4; ++n) acc[m][n] = z;

  gemm256_mainloop(A, Bt, H, H, H, row0, col0, lds, acc);

  const int lane = threadIdx.x & 63, w = threadIdx.x >> 6;
  const int wm = w >> 2, wn = w & 3;
  const int rbase = row0 + wm * 128 + (lane >> 4) * 4;
  const int cbase = col0 + wn * 64 + (lane & 15);
  if (col0 < 4096) {            // Q block
#pragma unroll
    for (int m = 0; m < 8; ++m)
#pragma unroll
      for (int n = 0; n < 4; ++n)
#pragma unroll
        for (int r = 0; r < 4; ++r) {
          int row = rbase + m * 16 + r;
          int col = cbase + n * 16;
          qb[((size_t)(col >> 8) * S + row) * D + (col & 255)] = f2bf(acc[m][n][r]);
        }
  } else if (col0 < 6144) {     // K block
#pragma unroll
    for (int m = 0; m < 8; ++m)
#pragma unroll
      for (int n = 0; n < 4; ++n)
#pragma unroll
        for (int r = 0; r < 4; ++r) {
          int row = rbase + m * 16 + r;
          int c2 = cbase + n * 16 - 4096;
          kbuf[((size_t)(c2 >> 8) * S + row) * D + (c2 & 255)] = f2bf(acc[m][n][r]);
        }
  } else {                      // V block (store transposed)
#pragma unroll
    for (int m = 0; m < 8; ++m)
#pragma unroll
      for (int n = 0; n < 4; ++n)
#pragma unroll
        for (int r = 0; r < 4; ++r) {
          int row = rbase + m * 16 + r;
          int c3 = cbase + n * 16 - 6144;
          vtb[((size_t)(c3 >> 8) * D + (c3 & 255)) * S + row] = f2bf(acc[m][n][r]);
        }
  }
}

// ---------------- GEMM 2: attn_out[S][4096] x woT[H rows][4096] -> d_out f32 ----------------
__global__ __launch_bounds__(512, 2) void gemm_out_kernel(const unsigned short* __restrict__ A,
                                                          const unsigned short* __restrict__ Bt,
                                                          float* __restrict__ C) {
  extern __shared__ char lds[];
  int bid = blockIdx.x;                 // 224 blocks
  bid = (bid & 7) * 28 + (bid >> 3);
  const int bx = bid & 15, by = bid >> 4;
  const int row0 = bx * 256, col0 = by * 256;
  f32x4 acc[8][4];
  f32x4 z = {0.f, 0.f, 0.f, 0.f};
#pragma unroll
  for (int m = 0; m < 8; ++m)
#pragma unroll
    for (int n = 0; n < 4; ++n) acc[m][n] = z;

  gemm256_mainloop(A, Bt, NQ * D, NQ * D, NQ * D, row0, col0, lds, acc);

  const int lane = threadIdx.x & 63, w = threadIdx.x >> 6;
  const int wm = w >> 2, wn = w & 3;
  const int rbase = row0 + wm * 128 + (lane >> 4) * 4;
  const int cbase = col0 + wn * 64 + (lane & 15);
#pragma unroll
  for (int m = 0; m < 8; ++m)
#pragma unroll
    for (int n = 0; n < 4; ++n)
#pragma unroll
      for (int r = 0; r < 4; ++r)
        C[(size_t)(rbase + m * 16 + r) * H + cbase + n * 16] = acc[m][n][r];
}

// ---------------- flash attention, split-KV: grid (32, NQ, 2) ----------------
// 256 threads = 4 waves; wave owns 32 q (2 subtiles of 16). LDS 52KB -> 3 blocks/CU:
// K double-buffered (2x16KB), V single-buffered (16KB, staged post-PV behind a barrier),
// P 4KB (per-wave 1KB reused across q-subtiles). Raw s_barrier + counted vmcnt (no drains).
// Fixed-max softmax (softcap bounds s<=50) => split partials combine by simple addition.
__global__ __launch_bounds__(256, 2) void attn_kernel(const unsigned short* __restrict__ q,
                                                      const unsigned short* __restrict__ kk_,
                                                      const unsigned short* __restrict__ vt,
                                                      const float* __restrict__ cs,
                                                      unsigned short* __restrict__ osp0,
                                                      unsigned short* __restrict__ osp1,
                                                      float* __restrict__ lbuf) {
  __shared__ __align__(16) char kl[2][16384];  // K tile [32 keys][256 d] bf16, swizzled
  __shared__ __align__(16) char vl[16384];     // Vt tile [256 d][32 keys] bf16, swizzled
  __shared__ __align__(16) char pl[4096];      // P per wave [16 q][32 keys] bf16, swizzled
  const int tid = threadIdx.x, lane = tid & 63, w = tid >> 6;
  const int h = blockIdx.y, hv = h >> 1;    // N_REP = 2
  const int sp = blockIdx.z;
  const int q0 = blockIdx.x * 128;
  const int ql = lane & 15;
  const int grp = lane >> 4;
  const int qw = q0 + w * 32;               // wave q base

  // split key range: tiles [kb0..kend]; lower floor(nt/2) tiles vs rest
  int lo = q0 - (WINDOW - 1); if (lo < 0) lo = 0;
  const int kb0 = lo & ~31;
  const int kend = q0 + 96;
  const int nt = ((kend - kb0) >> 5) + 1;
  const int nlow = nt >> 1;
  const int kbA = sp ? (kb0 + nlow * 32) : kb0;
  const int kbB = sp ? kend : (kb0 + (nlow - 1) * 32);

  // hoist Q fragments + apply RoPE in-register (partner of qf[t][j] is qf[t^4][j])
  bf16x8 qf[2][8];
#pragma unroll
  for (int qs = 0; qs < 2; ++qs) {
    const int row = qw + qs * 16 + ql;
    const unsigned short* qrow = q + ((size_t)h * S + row) * D;
#pragma unroll
    for (int t = 0; t < 8; ++t)
      qf[qs][t] = *(const bf16x8*)(qrow + t * 32 + grp * 8);
    const float* crow = cs + ((size_t)row << 7);
    const float* srow = crow + (size_t)S * 128;
#pragma unroll
    for (int t = 0; t < 4; ++t)
#pragma unroll
      for (int j = 0; j < 8; ++j) {
        const int dm = t * 32 + grp * 8 + j;
        const float c = crow[dm], s = srow[dm];
        const float lo2 = bf2f((unsigned short)qf[qs][t][j]);
        const float hi = bf2f((unsigned short)qf[qs][t + 4][j]);
        qf[qs][t][j]     = (short)f2bf(lo2 * c - hi * s);
        qf[qs][t + 4][j] = (short)f2bf(hi * c + lo2 * s);
      }
  }

  f32x4 oacc[2][16];
  f32x4 z = {0.f, 0.f, 0.f, 0.f};
#pragma unroll
  for (int qs = 0; qs < 2; ++qs)
#pragma unroll
    for (int i = 0; i < 16; ++i) oacc[qs][i] = z;
  float lrun[2] = {0.0f, 0.0f};

  const unsigned short* kbase = kk_ + (size_t)hv * S * D;
  const unsigned short* vbase = vt + (size_t)hv * D * S;
  int koff[4], voff[4];
#pragma unroll
  for (int j = 0; j < 4; ++j) {
    int c = w + 4 * j;
    int key = c * 2 + (lane >> 5);
    int colK = (((lane & 31) * 16) ^ ((key & 7) << 4)) >> 1;
    koff[j] = key * D + colK;
    int dd = c * 16 + (lane >> 2);
    int colV = (((lane & 3) * 16) ^ (((dd >> 1) & 3) << 4)) >> 1;
    voff[j] = dd * S + colV;
  }

  auto stageK = [&](int buf, int kb) {
#pragma unroll
    for (int j = 0; j < 4; ++j)
      load_lds16(kbase + (size_t)kb * D + koff[j], &kl[buf][(w + 4 * j) * 1024]);
  };
  auto stageV = [&](int kb) {
#pragma unroll
    for (int j = 0; j < 4; ++j)
      load_lds16(vbase + kb + voff[j], &vl[(w + 4 * j) * 1024]);
  };

  stageK(0, kbA);   // 4 loads (oldest)
  stageV(kbA);      // 4 loads
  int cur = 0;
  const int psw = ((ql >> 1) & 3) << 4;
  char* pw = pl + w * 1024;
  const int ksw = (ql & 7) << 4;

  for (int kb = kbA; kb <= kbB; kb += 32) {
    const bool more = (kb + 32 <= kbB);
    // [A] K(cur) ready (own oldest 4 = K); V may still be in flight
    asm volatile("s_waitcnt vmcnt(4)" ::: "memory");
    __builtin_amdgcn_s_barrier();
    asm volatile("" ::: "memory");
    if (more) stageK(cur ^ 1, kb + 32);

    // scores^T = K(32x256) x Q^T(256x32)
    f32x4 sacc[2][2];
    sacc[0][0] = z; sacc[0][1] = z; sacc[1][0] = z; sacc[1][1] = z;
#pragma unroll
    for (int t = 0; t < 8; ++t) {
      bf16x8 af[2];
#pragma unroll
      for (int ms = 0; ms < 2; ++ms)
        af[ms] = *(const bf16x8*)(kl[cur] + (ms * 16 + ql) * 512 + ((t * 64 + grp * 16) ^ ksw));
#pragma unroll
      for (int qs = 0; qs < 2; ++qs)
#pragma unroll
        for (int ms = 0; ms < 2; ++ms)
          sacc[qs][ms] = __builtin_amdgcn_mfma_f32_16x16x32_bf16(af[ms], qf[qs][t], sacc[qs][ms], 0, 0, 0);
    }

    // softcap+softmax (fixed max 50): p = exp(-100 / (exp(x*SCALE/25) + 1))
    bf16x8 pb[2];
#pragma unroll
    for (int qs = 0; qs < 2; ++qs) {
      const int qsb = qw + qs * 16;
      const int qg = qsb + ql;
      float pv[8];
#pragma unroll
      for (int i = 0; i < 8; ++i) {
        float x = sacc[qs][i >> 2][i & 3];
        float e = __expf(x * (SCALE / 25.0f));
        float rc = __builtin_amdgcn_rcpf(e + 1.0f);
        pv[i] = __expf(rc * -100.0f);
      }
      if (kb + 31 > qsb) {                 // causal edge
#pragma unroll
        for (int i = 0; i < 8; ++i) {
          int key = kb + (i >> 2) * 16 + grp * 4 + (i & 3);
          if (key > qg) pv[i] = 0.0f;
        }
      } else if (kb < qsb - 2032) {        // window edge
#pragma unroll
        for (int i = 0; i < 8; ++i) {
          int key = kb + (i >> 2) * 16 + grp * 4 + (i & 3);
          if (key <= qg - WINDOW) pv[i] = 0.0f;
        }
      }
#pragma unroll
      for (int i = 0; i < 8; ++i) lrun[qs] += pv[i];

      // P -> per-wave 1KB LDS (reused for both qs; in-order DS + lgkmcnt fences)
#pragma unroll
      for (int ms = 0; ms < 2; ++ms) {
        short4v pk;
        pk[0] = (short)f2bf(pv[ms * 4 + 0]);
        pk[1] = (short)f2bf(pv[ms * 4 + 1]);
        pk[2] = (short)f2bf(pv[ms * 4 + 2]);
        pk[3] = (short)f2bf(pv[ms * 4 + 3]);
        *(short4v*)(pw + ql * 64 + ((ms * 32 + grp * 8) ^ psw)) = pk;
      }
      asm volatile("s_waitcnt lgkmcnt(0)" ::: "memory");
      pb[qs] = *(const bf16x8*)(pw + ql * 64 + ((grp * 16) ^ psw));
      asm volatile("s_waitcnt lgkmcnt(0)" ::: "memory");
    }

    // [B] V(cur) ready: own oldest 4 = V if K(next) staged (vmcnt 4) else all (vmcnt 0)
    if (more) asm volatile("s_waitcnt vmcnt(4)" ::: "memory");
    else      asm volatile("s_waitcnt vmcnt(0)" ::: "memory");
    __builtin_amdgcn_s_barrier();
    asm volatile("" ::: "memory");

    // O^T += Vt(256x32) x P^T(32x32)
#pragma unroll
    for (int nt2 = 0; nt2 < 16; ++nt2) {
      int dr = nt2 * 16 + ql;
      bf16x8 va = *(const bf16x8*)(vl + dr * 64 + ((grp * 16) ^ (((dr >> 1) & 3) << 4)));
      oacc[0][nt2] = __builtin_amdgcn_mfma_f32_16x16x32_bf16(va, pb[0], oacc[0][nt2], 0, 0, 0);
      oacc[1][nt2] = __builtin_amdgcn_mfma_f32_16x16x32_bf16(va, pb[1], oacc[1][nt2], 0, 0, 0);
    }

    // [C] all waves done reading vl -> safe to restage V
    asm volatile("" ::: "memory");
    __builtin_amdgcn_s_barrier();
    asm volatile("" ::: "memory");
    if (more) stageV(kb + 32);
    cur ^= 1;
  }

  // epilogue: write UNNORMALIZED O (bf16) + l per q-row; combine kernel divides
  unsigned short* osp = sp ? osp1 : osp0;
#pragma unroll
  for (int qs = 0; qs < 2; ++qs) {
    float l = lrun[qs];
    l += __shfl_xor(l, 16);
    l += __shfl_xor(l, 32);
    const int row = qw + qs * 16 + ql;
    if (grp == 0) lbuf[((size_t)sp * NQ + h) * S + row] = l;
    unsigned short* orow = osp + (size_t)row * (NQ * D) + h * D;
#pragma unroll
    for (int nt2 = 0; nt2 < 16; ++nt2) {
      short4v o;
      o[0] = (short)f2bf(oacc[qs][nt2][0]);
      o[1] = (short)f2bf(oacc[qs][nt2][1]);
      o[2] = (short)f2bf(oacc[qs][nt2][2]);
      o[3] = (short)f2bf(oacc[qs][nt2][3]);
      *(short4v*)(orow + nt2 * 16 + grp * 4) = o;
    }
  }
}

// ---------------- combine: aob = (o0 + o1) / (l0 + l1), elementwise in-place on o0 ----------------
__global__ __launch_bounds__(256) void attn_combine_kernel(unsigned short* __restrict__ o0,
                                                           const unsigned short* __restrict__ o1,
                                                           const float* __restrict__ lbuf) {
  size_t base = ((size_t)blockIdx.x * 256 + threadIdx.x) * 8;
  const int row = (int)(base >> 12);
  const int h = (int)((base >> 8) & 15);
  float l = lbuf[(size_t)h * S + row] + lbuf[(size_t)(NQ + h) * S + row];
  float rl = 1.0f / fmaxf(l, 1e-35f);
  short8v a = *(const short8v*)(o0 + base);
  short8v b = *(const short8v*)(o1 + base);
  short8v o;
#pragma unroll
  for (int j = 0; j < 8; ++j)
    o[j] = (short)f2bf((bf2f((unsigned short)a[j]) + bf2f((unsigned short)b[j])) * rl);
  *(short8v*)(o0 + base) = o;
}

// ---------------- launch ----------------
extern "C" void kernel_launch(void* const* d_in, const int* in_sizes, int n_in,
                              void* d_out, int out_size, void* d_ws, size_t ws_size,
                              hipStream_t stream) {
  const float* hs = (const float*)d_in[0];
  const float* wq = (const float*)d_in[1];
  const float* wk = (const float*)d_in[2];
  const float* wv = (const float*)d_in[3];
  const float* wo = (const float*)d_in[4];
  float* out = (float*)d_out;

  char* ws = (char*)d_ws;
  size_t off = 0;
  auto alloc = [&](size_t bytes) {
    char* p = ws + off;
    off += (bytes + 255) & ~(size_t)255;
    return p;
  };
  unsigned short* hsb   = (unsigned short*)alloc((size_t)S * H * 2);
  unsigned short* wqkvT = (unsigned short*)alloc((size_t)8192 * H * 2);
  unsigned short* woT   = (unsigned short*)alloc((size_t)H * 4096 * 2);
  unsigned short* qb    = (unsigned short*)alloc((size_t)NQ * S * D * 2);
  unsigned short* kbuf  = (unsigned short*)alloc((size_t)NKV * S * D * 2);
  unsigned short* vtb   = (unsigned short*)alloc((size_t)NKV * D * S * 2);
  unsigned short* aob   = (unsigned short*)alloc((size_t)S * NQ * D * 2);   // split 0 / final
  unsigned short* aob1  = (unsigned short*)alloc((size_t)S * NQ * D * 2);   // split 1
  float*          lbuf  = (float*)alloc((size_t)2 * NQ * S * 4);
  float*          cs    = (float*)alloc((size_t)S * 128 * 2 * 4);
  if (off > ws_size) return;

  cast_hs_kernel<<<(S * H) / 2048, 256, 0, stream>>>(hs, hsb);
  transpose_cast_kernel<<<dim3(4096 / 64, H / 64), 256, 0, stream>>>(wq, wqkvT, H, 4096, H);
  transpose_cast_kernel<<<dim3(2048 / 64, H / 64), 256, 0, stream>>>(wk, wqkvT + (size_t)4096 * H, H, 2048, H);
  transpose_cast_kernel<<<dim3(2048 / 64, H / 64), 256, 0, stream>>>(wv, wqkvT + (size_t)6144 * H, H, 2048, H);
  transpose_cast_kernel<<<dim3(H / 64, 4096 / 64), 256, 0, stream>>>(wo, woT, 4096, H, 4096);
  rope_table_kernel<<<(S * 128) / 256, 256, 0, stream>>>(cs);
  gemm_qkv_kernel<<<512, 512, 131072, stream>>>(hsb, wqkvT, qb, kbuf, vtb);
  rope_apply_k_kernel<<<(NKV * S * 32) / 256, 256, 0, stream>>>(kbuf, cs);
  attn_kernel<<<dim3(S / 128, NQ, 2), 256, 0, stream>>>(qb, kbuf, vtb, cs, aob, aob1, lbuf);
  attn_combine_kernel<<<(S * NQ * D) / 2048, 256, 0, stream>>>(aob, aob1, lbuf);
  gemm_out_kernel<<<224, 512, 131072, stream>>>(aob, woT, out);
}

// Round 15
// 632.286 us; speedup vs baseline: 1.1007x; 1.1007x over previous
//
#include <hip/hip_runtime.h>
#include <hip/hip_bf16.h>
#include <cstdint>
#include <cstddef>

#define DEVFN __device__ __forceinline__

typedef __attribute__((ext_vector_type(4))) float f32x4;
typedef __attribute__((ext_vector_type(8))) short bf16x8;
typedef __attribute__((ext_vector_type(4))) short short4v;
typedef __attribute__((ext_vector_type(8))) short short8v;

static constexpr int S = 4096;
static constexpr int H = 3584;
static constexpr int NQ = 16;
static constexpr int NKV = 8;
static constexpr int D = 256;
static constexpr int WINDOW = 2048;
static constexpr float SCALE = 0.0625f;  // 256^-0.5

DEVFN unsigned short f2bf(float f) {
  union { float f; uint32_t u; } x; x.f = f;
  uint32_t u = x.u;
  u += 0x7fffu + ((u >> 16) & 1u);   // RNE
  return (unsigned short)(u >> 16);
}
DEVFN float bf2f(unsigned short h) {
  union { uint32_t u; float f; } x; x.u = ((uint32_t)h) << 16;
  return x.f;
}

DEVFN void load_lds16(const void* g, void* l) {
  __builtin_amdgcn_global_load_lds((const __attribute__((address_space(1))) void*)g,
                                   (__attribute__((address_space(3))) void*)l,
                                   16, 0, 0);
}

// ---------------- elementwise cast: hs f32 -> bf16 (8 elems/thread) ----------------
__global__ __launch_bounds__(256) void cast_hs_kernel(const float* __restrict__ in,
                                                      unsigned short* __restrict__ out) {
  int i = (blockIdx.x * 256 + threadIdx.x) * 8;
  float4 a = *(const float4*)(in + i);
  float4 b = *(const float4*)(in + i + 4);
  short8v o;
  o[0] = (short)f2bf(a.x); o[1] = (short)f2bf(a.y);
  o[2] = (short)f2bf(a.z); o[3] = (short)f2bf(a.w);
  o[4] = (short)f2bf(b.x); o[5] = (short)f2bf(b.y);
  o[6] = (short)f2bf(b.z); o[7] = (short)f2bf(b.w);
  *(short8v*)(out + i) = o;
}

// ---------------- transpose + cast: w[K][N] f32 -> wT[N][K] bf16, 64x64 tiles ----------------
__global__ __launch_bounds__(256) void transpose_cast_kernel(const float* __restrict__ in,
                                                             unsigned short* __restrict__ out,
                                                             int rows, int cols, int out_ld) {
  __shared__ float tile[64][65];
  const int r0 = blockIdx.y * 64, c0 = blockIdx.x * 64;
  const int t = threadIdx.x;
  const int rr = t >> 4, c4 = (t & 15) * 4;
#pragma unroll
  for (int j = 0; j < 4; ++j) {
    float4 v = *(const float4*)(in + (size_t)(r0 + rr + j * 16) * cols + c0 + c4);
    tile[rr + j * 16][c4 + 0] = v.x;
    tile[rr + j * 16][c4 + 1] = v.y;
    tile[rr + j * 16][c4 + 2] = v.z;
    tile[rr + j * 16][c4 + 3] = v.w;
  }
  __syncthreads();
  const int c = t >> 2, ch = (t & 3) * 16;
  short8v o0, o1;
#pragma unroll
  for (int j = 0; j < 8; ++j) o0[j] = (short)f2bf(tile[ch + j][c]);
#pragma unroll
  for (int j = 0; j < 8; ++j) o1[j] = (short)f2bf(tile[ch + 8 + j][c]);
  unsigned short* dst = out + (size_t)(c0 + c) * out_ld + r0 + ch;
  *(short8v*)dst = o0;
  *(short8v*)(dst + 8) = o1;
}

// ---------------- RoPE cos/sin table [S][128] x2 f32 ----------------
__global__ __launch_bounds__(256) void rope_table_kernel(float* __restrict__ cs) {
  int idx = blockIdx.x * 256 + threadIdx.x;  // S*128
  int s = idx >> 7, i = idx & 127;
  float inv = exp2f((float)i * -0.10381025296523007f);  // 10000^(-i/128)
  float f = (float)s * inv;
  cs[idx] = cosf(f);
  cs[(S * 128) + idx] = sinf(f);
}

// ---------------- RoPE apply in-place on K ONLY (bf16), 4 elems/thread ----------------
// (Q RoPE is folded into attn_kernel's register prologue.)
__global__ __launch_bounds__(256) void rope_apply_k_kernel(unsigned short* __restrict__ k,
                                                           const float* __restrict__ cs) {
  int idx = blockIdx.x * 256 + threadIdx.x;   // NKV*S*32
  int i4 = (idx & 31) * 4;
  int s = (idx >> 5) & (S - 1);
  int hh = idx >> 17;                          // 0..7
  unsigned short* base = k + ((size_t)hh * S + s) * D;
  float4 c  = *(const float4*)(cs + (s << 7) + i4);
  float4 sn = *(const float4*)(cs + (S * 128) + (s << 7) + i4);
  short4v a = *(short4v*)(base + i4);
  short4v b = *(short4v*)(base + i4 + 128);
  short4v o1, o2;
  o1[0] = (short)f2bf(bf2f((unsigned short)a[0]) * c.x - bf2f((unsigned short)b[0]) * sn.x);
  o1[1] = (short)f2bf(bf2f((unsigned short)a[1]) * c.y - bf2f((unsigned short)b[1]) * sn.y);
  o1[2] = (short)f2bf(bf2f((unsigned short)a[2]) * c.z - bf2f((unsigned short)b[2]) * sn.z);
  o1[3] = (short)f2bf(bf2f((unsigned short)a[3]) * c.w - bf2f((unsigned short)b[3]) * sn.w);
  o2[0] = (short)f2bf(bf2f((unsigned short)b[0]) * c.x + bf2f((unsigned short)a[0]) * sn.x);
  o2[1] = (short)f2bf(bf2f((unsigned short)b[1]) * c.y + bf2f((unsigned short)a[1]) * sn.y);
  o2[2] = (short)f2bf(bf2f((unsigned short)b[2]) * c.z + bf2f((unsigned short)a[2]) * sn.z);
  o2[3] = (short)f2bf(bf2f((unsigned short)b[3]) * c.w + bf2f((unsigned short)a[3]) * sn.w);
  *(short4v*)(base + i4) = o1;
  *(short4v*)(base + i4 + 128) = o2;
}

// ================== 256x256 8-phase GEMM (T2+T3+T4+T5) ==================
DEVFN void gemm256_mainloop(const unsigned short* __restrict__ A,
                            const unsigned short* __restrict__ Bt,
                            int Kdim, int lda, int ldb, int row0, int col0,
                            char* lds, f32x4 acc[8][4]) {
  const int tid = threadIdx.x, lane = tid & 63;
  const int w = tid >> 6;
  const int wm = w >> 2, wn = w & 3;
  const int NT = Kdim >> 6;

  const int u = ((tid & 7) * 16) ^ (((tid >> 3) & 7) << 4);
  const int srow = (tid >> 3) + (u >> 6) * 128;
  const int sc = (u & 63) >> 1;

  const unsigned short* aSrc = A + (size_t)(row0 + srow) * lda + sc;
  const unsigned short* bSrc = Bt + (size_t)(col0 + srow) * ldb + sc;
  const size_t aj = (size_t)64 * lda, bj = (size_t)64 * ldb;

  char* const dA = lds + tid * 16;
  char* const dB = lds + 32768 + tid * 16;

  const int aoff = (lane & 15) * 128 + ((((lane >> 4) * 16) + wm * 64) ^ ((lane & 7) << 4));
  const int boff = ((wn & 1) * 64 + (lane & 15)) * 128 +
                   ((((lane >> 4) * 16) + (wn >> 1) * 64) ^ ((lane & 7) << 4));

#define STAGE_A(kt2, kh) do { \
    char* d_ = dA + (((kt2) & 1) << 16) + ((kh) << 14); \
    const unsigned short* s_ = aSrc + (kt2) * 64 + (kh) * 32; \
    load_lds16(s_, d_); load_lds16(s_ + aj, d_ + 8192); } while (0)
#define STAGE_B(kt2, kh) do { \
    char* d_ = dB + (((kt2) & 1) << 16) + ((kh) << 14); \
    const unsigned short* s_ = bSrc + (kt2) * 64 + (kh) * 32; \
    load_lds16(s_, d_); load_lds16(s_ + bj, d_ + 8192); } while (0)

  STAGE_A(0, 0); STAGE_B(0, 0); STAGE_A(0, 1); STAGE_B(0, 1);
  if (NT > 1) { STAGE_A(1, 0); STAGE_B(1, 0); }
  asm volatile("s_waitcnt vmcnt(4)" ::: "memory");
  __builtin_amdgcn_s_barrier();
  asm volatile("" ::: "memory");

  for (int kt = 0; kt < NT; ++kt) {
    const char* lA = lds + ((kt & 1) << 16) + aoff;
    const char* lB = lds + ((kt & 1) << 16) + 32768 + boff;
    bf16x8 bfr[4];
#pragma unroll
    for (int ph = 0; ph < 4; ++ph) {
      const int kh = ph >> 1;
      const int mh = ph & 1;
      bf16x8 af[4];
#pragma unroll
      for (int j = 0; j < 4; ++j)
        af[j] = *(const bf16x8*)(lA + (kh << 14) + (mh * 4 + j) * 2048);
      if (mh == 0) {
#pragma unroll
        for (int n = 0; n < 4; ++n)
          bfr[n] = *(const bf16x8*)(lB + (kh << 14) + n * 2048);
      }
      if (ph == 0)      { if (kt + 1 < NT) STAGE_A(kt + 1, 1); }
      else if (ph == 1) { if (kt + 1 < NT) STAGE_B(kt + 1, 1); }
      else if (ph == 2) { if (kt + 2 < NT) STAGE_A(kt + 2, 0); }
      else              { if (kt + 2 < NT) STAGE_B(kt + 2, 0); }

      asm volatile("" ::: "memory");
      __builtin_amdgcn_s_barrier();
      asm volatile("" ::: "memory");
      __builtin_amdgcn_s_setprio(1);
#pragma unroll
      for (int j = 0; j < 4; ++j)
#pragma unroll
        for (int n = 0; n < 4; ++n)
          acc[mh * 4 + j][n] =
              __builtin_amdgcn_mfma_f32_16x16x32_bf16(af[j], bfr[n], acc[mh * 4 + j][n], 0, 0, 0);
      __builtin_amdgcn_s_setprio(0);
      if (ph == 3) {
        if (kt < NT - 2) asm volatile("s_waitcnt vmcnt(4)" ::: "memory");
        else             asm volatile("s_waitcnt vmcnt(0)" ::: "memory");
      }
      asm volatile("" ::: "memory");
      __builtin_amdgcn_s_barrier();
      asm volatile("" ::: "memory");
    }
  }
#undef STAGE_A
#undef STAGE_B
}

// ---------------- GEMM 1: [S][H] x [H][8192] -> scatter to q, k, vt ----------------
__global__ __launch_bounds__(512, 2) void gemm_qkv_kernel(const unsigned short* __restrict__ A,
                                                          const unsigned short* __restrict__ Bt,
                                                          unsigned short* __restrict__ qb,
                                                          unsigned short* __restrict__ kbuf,
                                                          unsigned short* __restrict__ vtb) {
  extern __shared__ char lds[];
  int bid = blockIdx.x;                 // 512 blocks
  bid = (bid & 7) * 64 + (bid >> 3);    // bijective XCD swizzle
  const int bx = bid & 15, by = bid >> 4;
  const int row0 = bx * 256, col0 = by * 256;
  f32x4 acc[8][4];
  f32x4 z = {0.f, 0.f, 0.f, 0.f};
#pragma unroll
  for (int m = 0; m < 8; ++m)
#pragma unroll
    for (int n = 0; n < 4; ++n) acc[m][n] = z;

  gemm256_mainloop(A, Bt, H, H, H, row0, col0, lds, acc);

  const int lane = threadIdx.x & 63, w = threadIdx.x >> 6;
  const int wm = w >> 2, wn = w & 3;
  const int rbase = row0 + wm * 128 + (lane >> 4) * 4;
  const int cbase = col0 + wn * 64 + (lane & 15);
  if (col0 < 4096) {            // Q block
#pragma unroll
    for (int m = 0; m < 8; ++m)
#pragma unroll
      for (int n = 0; n < 4; ++n)
#pragma unroll
        for (int r = 0; r < 4; ++r) {
          int row = rbase + m * 16 + r;
          int col = cbase + n * 16;
          qb[((size_t)(col >> 8) * S + row) * D + (col & 255)] = f2bf(acc[m][n][r]);
        }
  } else if (col0 < 6144) {     // K block
#pragma unroll
    for (int m = 0; m < 8; ++m)
#pragma unroll
      for (int n = 0; n < 4; ++n)
#pragma unroll
        for (int r = 0; r < 4; ++r) {
          int row = rbase + m * 16 + r;
          int c2 = cbase + n * 16 - 4096;
          kbuf[((size_t)(c2 >> 8) * S + row) * D + (c2 & 255)] = f2bf(acc[m][n][r]);
        }
  } else {                      // V block (store transposed)
#pragma unroll
    for (int m = 0; m < 8; ++m)
#pragma unroll
      for (int n = 0; n < 4; ++n)
#pragma unroll
        for (int r = 0; r < 4; ++r) {
          int row = rbase + m * 16 + r;
          int c3 = cbase + n * 16 - 6144;
          vtb[((size_t)(c3 >> 8) * D + (c3 & 255)) * S + row] = f2bf(acc[m][n][r]);
        }
  }
}

// ---------------- GEMM 2: attn_out[S][4096] x woT[H rows][4096] -> d_out f32 ----------------
__global__ __launch_bounds__(512, 2) void gemm_out_kernel(const unsigned short* __restrict__ A,
                                                          const unsigned short* __restrict__ Bt,
                                                          float* __restrict__ C) {
  extern __shared__ char lds[];
  int bid = blockIdx.x;                 // 224 blocks
  bid = (bid & 7) * 28 + (bid >> 3);
  const int bx = bid & 15, by = bid >> 4;
  const int row0 = bx * 256, col0 = by * 256;
  f32x4 acc[8][4];
  f32x4 z = {0.f, 0.f, 0.f, 0.f};
#pragma unroll
  for (int m = 0; m < 8; ++m)
#pragma unroll
    for (int n = 0; n < 4; ++n) acc[m][n] = z;

  gemm256_mainloop(A, Bt, NQ * D, NQ * D, NQ * D, row0, col0, lds, acc);

  const int lane = threadIdx.x & 63, w = threadIdx.x >> 6;
  const int wm = w >> 2, wn = w & 3;
  const int rbase = row0 + wm * 128 + (lane >> 4) * 4;
  const int cbase = col0 + wn * 64 + (lane & 15);
#pragma unroll
  for (int m = 0; m < 8; ++m)
#pragma unroll
    for (int n = 0; n < 4; ++n)
#pragma unroll
      for (int r = 0; r < 4; ++r)
        C[(size_t)(rbase + m * 16 + r) * H + cbase + n * 16] = acc[m][n][r];
}

// ---------------- flash attention: K/V/P in LDS, 2-exp softcap, Q-RoPE in prologue ----------------
// grid (S/128, NQ), 256 threads = 4 waves; wave w owns 32 q (2 subtiles of 16).
__global__ __launch_bounds__(256, 2) void attn_kernel(const unsigned short* __restrict__ q,
                                                      const unsigned short* __restrict__ kk_,
                                                      const unsigned short* __restrict__ vt,
                                                      const float* __restrict__ cs,
                                                      unsigned short* __restrict__ aout) {
  __shared__ __align__(16) char kl[2][16384];  // K tile [32 keys][256 d] bf16, swizzled
  __shared__ __align__(16) char vl[2][16384];  // Vt tile [256 d][32 keys] bf16, swizzled
  __shared__ __align__(16) char pl[8192];      // P per wave [32 q][32 keys] bf16, swizzled
  const int tid = threadIdx.x, lane = tid & 63, w = tid >> 6;
  const int h = blockIdx.y, hv = h >> 1;    // N_REP = 2
  const int q0 = blockIdx.x * 128;
  const int ql = lane & 15;
  const int grp = lane >> 4;
  const int qw = q0 + w * 32;               // wave q base

  // hoist Q fragments + apply RoPE in-register (partner of qf[t][j] is qf[t^4][j])
  bf16x8 qf[2][8];
#pragma unroll
  for (int qs = 0; qs < 2; ++qs) {
    const int row = qw + qs * 16 + ql;
    const unsigned short* qrow = q + ((size_t)h * S + row) * D;
#pragma unroll
    for (int t = 0; t < 8; ++t)
      qf[qs][t] = *(const bf16x8*)(qrow + t * 32 + grp * 8);
    const float* crow = cs + ((size_t)row << 7);
    const float* srow = crow + (size_t)S * 128;
#pragma unroll
    for (int t = 0; t < 4; ++t)
#pragma unroll
      for (int j = 0; j < 8; ++j) {
        const int dm = t * 32 + grp * 8 + j;
        const float c = crow[dm], s = srow[dm];
        const float lo = bf2f((unsigned short)qf[qs][t][j]);
        const float hi = bf2f((unsigned short)qf[qs][t + 4][j]);
        qf[qs][t][j]     = (short)f2bf(lo * c - hi * s);
        qf[qs][t + 4][j] = (short)f2bf(hi * c + lo * s);
      }
  }

  f32x4 oacc[2][16];
  f32x4 z = {0.f, 0.f, 0.f, 0.f};
#pragma unroll
  for (int qs = 0; qs < 2; ++qs)
#pragma unroll
    for (int i = 0; i < 16; ++i) oacc[qs][i] = z;
  float lrun[2] = {0.0f, 0.0f};

  int lo = q0 - (WINDOW - 1); if (lo < 0) lo = 0;
  const int kb0 = lo & ~31;
  const int kend = q0 + 96;

  const unsigned short* kbase = kk_ + (size_t)hv * S * D;
  const unsigned short* vbase = vt + (size_t)hv * D * S;
  int koff[4], voff[4];
#pragma unroll
  for (int j = 0; j < 4; ++j) {
    int c = w + 4 * j;
    int key = c * 2 + (lane >> 5);
    int colK = (((lane & 31) * 16) ^ ((key & 7) << 4)) >> 1;
    koff[j] = key * D + colK;
    int dd = c * 16 + (lane >> 2);
    int colV = (((lane & 3) * 16) ^ (((dd >> 1) & 3) << 4)) >> 1;
    voff[j] = dd * S + colV;
  }

  auto stage = [&](int buf, int kb) {
#pragma unroll
    for (int j = 0; j < 4; ++j) {
      int c = w + 4 * j;
      load_lds16(kbase + (size_t)kb * D + koff[j], &kl[buf][c * 1024]);
      load_lds16(vbase + kb + voff[j], &vl[buf][c * 1024]);
    }
  };

  stage(0, kb0);
  int cur = 0;
  const int psw = ((ql >> 1) & 3) << 4;
  char* pw = pl + w * 2048;
  const int ksw = (ql & 7) << 4;

  for (int kb = kb0; kb <= kend; kb += 32) {
    __syncthreads();
    if (kb + 32 <= kend) stage(cur ^ 1, kb + 32);

    // scores^T = K(32x256) x Q^T(256x32): A-frag (K) reused across both q-subs
    f32x4 sacc[2][2];
    sacc[0][0] = z; sacc[0][1] = z; sacc[1][0] = z; sacc[1][1] = z;
#pragma unroll
    for (int t = 0; t < 8; ++t) {
      bf16x8 af[2];
#pragma unroll
      for (int ms = 0; ms < 2; ++ms)
        af[ms] = *(const bf16x8*)(kl[cur] + (ms * 16 + ql) * 512 + ((t * 64 + grp * 16) ^ ksw));
#pragma unroll
      for (int qs = 0; qs < 2; ++qs)
#pragma unroll
        for (int ms = 0; ms < 2; ++ms)
          sacc[qs][ms] = __builtin_amdgcn_mfma_f32_16x16x32_bf16(af[ms], qf[qs][t], sacc[qs][ms], 0, 0, 0);
    }

    // fused softcap+softmax vs fixed max 50: p = exp(-100 / (exp(x*SCALE/25) + 1))
#pragma unroll
    for (int qs = 0; qs < 2; ++qs) {
      const int qsb = qw + qs * 16;
      const int qg = qsb + ql;
      float pv[8];
#pragma unroll
      for (int i = 0; i < 8; ++i) {
        float x = sacc[qs][i >> 2][i & 3];
        float e = __expf(x * (SCALE / 25.0f));
        float rc = __builtin_amdgcn_rcpf(e + 1.0f);
        pv[i] = __expf(rc * -100.0f);
      }
      if (kb + 31 > qsb) {                 // causal edge
#pragma unroll
        for (int i = 0; i < 8; ++i) {
          int key = kb + (i >> 2) * 16 + grp * 4 + (i & 3);
          if (key > qg) pv[i] = 0.0f;
        }
      } else if (kb < qsb - 2032) {        // window edge
#pragma unroll
        for (int i = 0; i < 8; ++i) {
          int key = kb + (i >> 2) * 16 + grp * 4 + (i & 3);
          if (key <= qg - WINDOW) pv[i] = 0.0f;
        }
      }
#pragma unroll
      for (int i = 0; i < 8; ++i) lrun[qs] += pv[i];

#pragma unroll
      for (int ms = 0; ms < 2; ++ms) {
        short4v pk;
        pk[0] = (short)f2bf(pv[ms * 4 + 0]);
        pk[1] = (short)f2bf(pv[ms * 4 + 1]);
        pk[2] = (short)f2bf(pv[ms * 4 + 2]);
        pk[3] = (short)f2bf(pv[ms * 4 + 3]);
        *(short4v*)(pw + (qs * 16 + ql) * 64 + ((ms * 32 + grp * 8) ^ psw)) = pk;
      }
    }
    asm volatile("s_waitcnt lgkmcnt(0)" ::: "memory");
    bf16x8 pb[2];
#pragma unroll
    for (int qs = 0; qs < 2; ++qs)
      pb[qs] = *(const bf16x8*)(pw + (qs * 16 + ql) * 64 + ((grp * 16) ^ psw));

    // O^T += Vt(256x32) x P^T(32x32): V A-frag reused across both q-subs
#pragma unroll
    for (int nt = 0; nt < 16; ++nt) {
      int dr = nt * 16 + ql;
      bf16x8 va = *(const bf16x8*)(vl[cur] + dr * 64 + ((grp * 16) ^ (((dr >> 1) & 3) << 4)));
      oacc[0][nt] = __builtin_amdgcn_mfma_f32_16x16x32_bf16(va, pb[0], oacc[0][nt], 0, 0, 0);
      oacc[1][nt] = __builtin_amdgcn_mfma_f32_16x16x32_bf16(va, pb[1], oacc[1][nt], 0, 0, 0);
    }
    cur ^= 1;
  }

  // epilogue: reduce l across the 4 lane-groups (same q col), normalize, store
#pragma unroll
  for (int qs = 0; qs < 2; ++qs) {
    float l = lrun[qs];
    l += __shfl_xor(l, 16);
    l += __shfl_xor(l, 32);
    l = fmaxf(l, 1e-35f);
    float rl = 1.0f / l;
    unsigned short* orow = aout + (size_t)(qw + qs * 16 + ql) * (NQ * D) + h * D;
#pragma unroll
    for (int nt = 0; nt < 16; ++nt) {
      short4v o;
      o[0] = (short)f2bf(oacc[qs][nt][0] * rl);
      o[1] = (short)f2bf(oacc[qs][nt][1] * rl);
      o[2] = (short)f2bf(oacc[qs][nt][2] * rl);
      o[3] = (short)f2bf(oacc[qs][nt][3] * rl);
      *(short4v*)(orow + nt * 16 + grp * 4) = o;
    }
  }
}

// ---------------- launch ----------------
extern "C" void kernel_launch(void* const* d_in, const int* in_sizes, int n_in,
                              void* d_out, int out_size, void* d_ws, size_t ws_size,
                              hipStream_t stream) {
  const float* hs = (const float*)d_in[0];
  const float* wq = (const float*)d_in[1];
  const float* wk = (const float*)d_in[2];
  const float* wv = (const float*)d_in[3];
  const float* wo = (const float*)d_in[4];
  float* out = (float*)d_out;

  char* ws = (char*)d_ws;
  size_t off = 0;
  auto alloc = [&](size_t bytes) {
    char* p = ws + off;
    off += (bytes + 255) & ~(size_t)255;
    return p;
  };
  unsigned short* hsb   = (unsigned short*)alloc((size_t)S * H * 2);
  unsigned short* wqkvT = (unsigned short*)alloc((size_t)8192 * H * 2);
  unsigned short* woT   = (unsigned short*)alloc((size_t)H * 4096 * 2);
  unsigned short* qb    = (unsigned short*)alloc((size_t)NQ * S * D * 2);
  unsigned short* kbuf  = (unsigned short*)alloc((size_t)NKV * S * D * 2);
  unsigned short* vtb   = (unsigned short*)alloc((size_t)NKV * D * S * 2);
  unsigned short* aob   = (unsigned short*)alloc((size_t)S * NQ * D * 2);
  float*          cs    = (float*)alloc((size_t)S * 128 * 2 * 4);
  if (off > ws_size) return;

  cast_hs_kernel<<<(S * H) / 2048, 256, 0, stream>>>(hs, hsb);
  transpose_cast_kernel<<<dim3(4096 / 64, H / 64), 256, 0, stream>>>(wq, wqkvT, H, 4096, H);
  transpose_cast_kernel<<<dim3(2048 / 64, H / 64), 256, 0, stream>>>(wk, wqkvT + (size_t)4096 * H, H, 2048, H);
  transpose_cast_kernel<<<dim3(2048 / 64, H / 64), 256, 0, stream>>>(wv, wqkvT + (size_t)6144 * H, H, 2048, H);
  transpose_cast_kernel<<<dim3(H / 64, 4096 / 64), 256, 0, stream>>>(wo, woT, 4096, H, 4096);
  rope_table_kernel<<<(S * 128) / 256, 256, 0, stream>>>(cs);
  gemm_qkv_kernel<<<512, 512, 131072, stream>>>(hsb, wqkvT, qb, kbuf, vtb);
  rope_apply_k_kernel<<<(NKV * S * 32) / 256, 256, 0, stream>>>(kbuf, cs);
  attn_kernel<<<dim3(S / 128, NQ), 256, 0, stream>>>(qb, kbuf, vtb, cs, aob);
  gemm_out_kernel<<<224, 512, 131072, stream>>>(aob, woT, out);
}

// Round 16
// 614.205 us; speedup vs baseline: 1.1331x; 1.0294x over previous
//
#include <hip/hip_runtime.h>
#include <hip/hip_bf16.h>
#include <cstdint>
#include <cstddef>

#define DEVFN __device__ __forceinline__

typedef __attribute__((ext_vector_type(4))) float f32x4;
typedef __attribute__((ext_vector_type(8))) short bf16x8;
typedef __attribute__((ext_vector_type(4))) short short4v;
typedef __attribute__((ext_vector_type(8))) short short8v;

static constexpr int S = 4096;
static constexpr int H = 3584;
static constexpr int NQ = 16;
static constexpr int NKV = 8;
static constexpr int D = 256;
static constexpr int WINDOW = 2048;
static constexpr float SCALE = 0.0625f;  // 256^-0.5

DEVFN unsigned short f2bf(float f) {
  union { float f; uint32_t u; } x; x.f = f;
  uint32_t u = x.u;
  u += 0x7fffu + ((u >> 16) & 1u);   // RNE
  return (unsigned short)(u >> 16);
}
DEVFN float bf2f(unsigned short h) {
  union { uint32_t u; float f; } x; x.u = ((uint32_t)h) << 16;
  return x.f;
}

DEVFN void load_lds16(const void* g, void* l) {
  __builtin_amdgcn_global_load_lds((const __attribute__((address_space(1))) void*)g,
                                   (__attribute__((address_space(3))) void*)l,
                                   16, 0, 0);
}

// ---------------- elementwise cast: hs f32 -> bf16 (8 elems/thread) ----------------
__global__ __launch_bounds__(256) void cast_hs_kernel(const float* __restrict__ in,
                                                      unsigned short* __restrict__ out) {
  int i = (blockIdx.x * 256 + threadIdx.x) * 8;
  float4 a = *(const float4*)(in + i);
  float4 b = *(const float4*)(in + i + 4);
  short8v o;
  o[0] = (short)f2bf(a.x); o[1] = (short)f2bf(a.y);
  o[2] = (short)f2bf(a.z); o[3] = (short)f2bf(a.w);
  o[4] = (short)f2bf(b.x); o[5] = (short)f2bf(b.y);
  o[6] = (short)f2bf(b.z); o[7] = (short)f2bf(b.w);
  *(short8v*)(out + i) = o;
}

// ---------------- transpose + cast: w[K][N] f32 -> wT[N][K] bf16, 64x64 tiles ----------------
__global__ __launch_bounds__(256) void transpose_cast_kernel(const float* __restrict__ in,
                                                             unsigned short* __restrict__ out,
                                                             int rows, int cols, int out_ld) {
  __shared__ float tile[64][65];
  const int r0 = blockIdx.y * 64, c0 = blockIdx.x * 64;
  const int t = threadIdx.x;
  const int rr = t >> 4, c4 = (t & 15) * 4;
#pragma unroll
  for (int j = 0; j < 4; ++j) {
    float4 v = *(const float4*)(in + (size_t)(r0 + rr + j * 16) * cols + c0 + c4);
    tile[rr + j * 16][c4 + 0] = v.x;
    tile[rr + j * 16][c4 + 1] = v.y;
    tile[rr + j * 16][c4 + 2] = v.z;
    tile[rr + j * 16][c4 + 3] = v.w;
  }
  __syncthreads();
  const int c = t >> 2, ch = (t & 3) * 16;
  short8v o0, o1;
#pragma unroll
  for (int j = 0; j < 8; ++j) o0[j] = (short)f2bf(tile[ch + j][c]);
#pragma unroll
  for (int j = 0; j < 8; ++j) o1[j] = (short)f2bf(tile[ch + 8 + j][c]);
  unsigned short* dst = out + (size_t)(c0 + c) * out_ld + r0 + ch;
  *(short8v*)dst = o0;
  *(short8v*)(dst + 8) = o1;
}

// ---------------- RoPE cos/sin table [S][128] x2 f32 ----------------
__global__ __launch_bounds__(256) void rope_table_kernel(float* __restrict__ cs) {
  int idx = blockIdx.x * 256 + threadIdx.x;  // S*128
  int s = idx >> 7, i = idx & 127;
  float inv = exp2f((float)i * -0.10381025296523007f);  // 10000^(-i/128)
  float f = (float)s * inv;
  cs[idx] = cosf(f);
  cs[(S * 128) + idx] = sinf(f);
}

// ---------------- RoPE apply in-place on K ONLY (bf16), 4 elems/thread ----------------
// (Q RoPE is folded into attn_kernel's register prologue.)
__global__ __launch_bounds__(256) void rope_apply_k_kernel(unsigned short* __restrict__ k,
                                                           const float* __restrict__ cs) {
  int idx = blockIdx.x * 256 + threadIdx.x;   // NKV*S*32
  int i4 = (idx & 31) * 4;
  int s = (idx >> 5) & (S - 1);
  int hh = idx >> 17;                          // 0..7
  unsigned short* base = k + ((size_t)hh * S + s) * D;
  float4 c  = *(const float4*)(cs + (s << 7) + i4);
  float4 sn = *(const float4*)(cs + (S * 128) + (s << 7) + i4);
  short4v a = *(short4v*)(base + i4);
  short4v b = *(short4v*)(base + i4 + 128);
  short4v o1, o2;
  o1[0] = (short)f2bf(bf2f((unsigned short)a[0]) * c.x - bf2f((unsigned short)b[0]) * sn.x);
  o1[1] = (short)f2bf(bf2f((unsigned short)a[1]) * c.y - bf2f((unsigned short)b[1]) * sn.y);
  o1[2] = (short)f2bf(bf2f((unsigned short)a[2]) * c.z - bf2f((unsigned short)b[2]) * sn.z);
  o1[3] = (short)f2bf(bf2f((unsigned short)a[3]) * c.w - bf2f((unsigned short)b[3]) * sn.w);
  o2[0] = (short)f2bf(bf2f((unsigned short)b[0]) * c.x + bf2f((unsigned short)a[0]) * sn.x);
  o2[1] = (short)f2bf(bf2f((unsigned short)b[1]) * c.y + bf2f((unsigned short)a[1]) * sn.y);
  o2[2] = (short)f2bf(bf2f((unsigned short)b[2]) * c.z + bf2f((unsigned short)a[2]) * sn.z);
  o2[3] = (short)f2bf(bf2f((unsigned short)b[3]) * c.w + bf2f((unsigned short)a[3]) * sn.w);
  *(short4v*)(base + i4) = o1;
  *(short4v*)(base + i4 + 128) = o2;
}

// ================== 256x256 8-phase GEMM (T2+T3+T4+T5) ==================
DEVFN void gemm256_mainloop(const unsigned short* __restrict__ A,
                            const unsigned short* __restrict__ Bt,
                            int Kdim, int lda, int ldb, int row0, int col0,
                            char* lds, f32x4 acc[8][4]) {
  const int tid = threadIdx.x, lane = tid & 63;
  const int w = tid >> 6;
  const int wm = w >> 2, wn = w & 3;
  const int NT = Kdim >> 6;

  const int u = ((tid & 7) * 16) ^ (((tid >> 3) & 7) << 4);
  const int srow = (tid >> 3) + (u >> 6) * 128;
  const int sc = (u & 63) >> 1;

  const unsigned short* aSrc = A + (size_t)(row0 + srow) * lda + sc;
  const unsigned short* bSrc = Bt + (size_t)(col0 + srow) * ldb + sc;
  const size_t aj = (size_t)64 * lda, bj = (size_t)64 * ldb;

  char* const dA = lds + tid * 16;
  char* const dB = lds + 32768 + tid * 16;

  const int aoff = (lane & 15) * 128 + ((((lane >> 4) * 16) + wm * 64) ^ ((lane & 7) << 4));
  const int boff = ((wn & 1) * 64 + (lane & 15)) * 128 +
                   ((((lane >> 4) * 16) + (wn >> 1) * 64) ^ ((lane & 7) << 4));

#define STAGE_A(kt2, kh) do { \
    char* d_ = dA + (((kt2) & 1) << 16) + ((kh) << 14); \
    const unsigned short* s_ = aSrc + (kt2) * 64 + (kh) * 32; \
    load_lds16(s_, d_); load_lds16(s_ + aj, d_ + 8192); } while (0)
#define STAGE_B(kt2, kh) do { \
    char* d_ = dB + (((kt2) & 1) << 16) + ((kh) << 14); \
    const unsigned short* s_ = bSrc + (kt2) * 64 + (kh) * 32; \
    load_lds16(s_, d_); load_lds16(s_ + bj, d_ + 8192); } while (0)

  STAGE_A(0, 0); STAGE_B(0, 0); STAGE_A(0, 1); STAGE_B(0, 1);
  if (NT > 1) { STAGE_A(1, 0); STAGE_B(1, 0); }
  asm volatile("s_waitcnt vmcnt(4)" ::: "memory");
  __builtin_amdgcn_s_barrier();
  asm volatile("" ::: "memory");

  for (int kt = 0; kt < NT; ++kt) {
    const char* lA = lds + ((kt & 1) << 16) + aoff;
    const char* lB = lds + ((kt & 1) << 16) + 32768 + boff;
    bf16x8 bfr[4];
#pragma unroll
    for (int ph = 0; ph < 4; ++ph) {
      const int kh = ph >> 1;
      const int mh = ph & 1;
      bf16x8 af[4];
#pragma unroll
      for (int j = 0; j < 4; ++j)
        af[j] = *(const bf16x8*)(lA + (kh << 14) + (mh * 4 + j) * 2048);
      if (mh == 0) {
#pragma unroll
        for (int n = 0; n < 4; ++n)
          bfr[n] = *(const bf16x8*)(lB + (kh << 14) + n * 2048);
      }
      if (ph == 0)      { if (kt + 1 < NT) STAGE_A(kt + 1, 1); }
      else if (ph == 1) { if (kt + 1 < NT) STAGE_B(kt + 1, 1); }
      else if (ph == 2) { if (kt + 2 < NT) STAGE_A(kt + 2, 0); }
      else              { if (kt + 2 < NT) STAGE_B(kt + 2, 0); }

      asm volatile("" ::: "memory");
      __builtin_amdgcn_s_barrier();
      asm volatile("" ::: "memory");
      __builtin_amdgcn_s_setprio(1);
#pragma unroll
      for (int j = 0; j < 4; ++j)
#pragma unroll
        for (int n = 0; n < 4; ++n)
          acc[mh * 4 + j][n] =
              __builtin_amdgcn_mfma_f32_16x16x32_bf16(af[j], bfr[n], acc[mh * 4 + j][n], 0, 0, 0);
      __builtin_amdgcn_s_setprio(0);
      if (ph == 3) {
        if (kt < NT - 2) asm volatile("s_waitcnt vmcnt(4)" ::: "memory");
        else             asm volatile("s_waitcnt vmcnt(0)" ::: "memory");
      }
      asm volatile("" ::: "memory");
      __builtin_amdgcn_s_barrier();
      asm volatile("" ::: "memory");
    }
  }
#undef STAGE_A
#undef STAGE_B
}

// ---------------- GEMM 1: [S][H] x [H][8192] -> scatter to q, k, vt ----------------
__global__ __launch_bounds__(512, 2) void gemm_qkv_kernel(const unsigned short* __restrict__ A,
                                                          const unsigned short* __restrict__ Bt,
                                                          unsigned short* __restrict__ qb,
                                                          unsigned short* __restrict__ kbuf,
                                                          unsigned short* __restrict__ vtb) {
  extern __shared__ char lds[];
  int bid = blockIdx.x;                 // 512 blocks
  bid = (bid & 7) * 64 + (bid >> 3);    // bijective XCD swizzle
  const int bx = bid & 15, by = bid >> 4;
  const int row0 = bx * 256, col0 = by * 256;
  f32x4 acc[8][4];
  f32x4 z = {0.f, 0.f, 0.f, 0.f};
#pragma unroll
  for (int m = 0; m < 8; ++m)
#pragma unroll
    for (int n = 0; n < 4; ++n) acc[m][n] = z;

  gemm256_mainloop(A, Bt, H, H, H, row0, col0, lds, acc);

  const int lane = threadIdx.x & 63, w = threadIdx.x >> 6;
  const int wm = w >> 2, wn = w & 3;
  const int rbase = row0 + wm * 128 + (lane >> 4) * 4;
  const int cbase = col0 + wn * 64 + (lane & 15);
  if (col0 < 4096) {            // Q block
#pragma unroll
    for (int m = 0; m < 8; ++m)
#pragma unroll
      for (int n = 0; n < 4; ++n)
#pragma unroll
        for (int r = 0; r < 4; ++r) {
          int row = rbase + m * 16 + r;
          int col = cbase + n * 16;
          qb[((size_t)(col >> 8) * S + row) * D + (col & 255)] = f2bf(acc[m][n][r]);
        }
  } else if (col0 < 6144) {     // K block
#pragma unroll
    for (int m = 0; m < 8; ++m)
#pragma unroll
      for (int n = 0; n < 4; ++n)
#pragma unroll
        for (int r = 0; r < 4; ++r) {
          int row = rbase + m * 16 + r;
          int c2 = cbase + n * 16 - 4096;
          kbuf[((size_t)(c2 >> 8) * S + row) * D + (c2 & 255)] = f2bf(acc[m][n][r]);
        }
  } else {                      // V block (store transposed)
#pragma unroll
    for (int m = 0; m < 8; ++m)
#pragma unroll
      for (int n = 0; n < 4; ++n)
#pragma unroll
        for (int r = 0; r < 4; ++r) {
          int row = rbase + m * 16 + r;
          int c3 = cbase + n * 16 - 6144;
          vtb[((size_t)(c3 >> 8) * D + (c3 & 255)) * S + row] = f2bf(acc[m][n][r]);
        }
  }
}

// ---------------- GEMM 2: attn_out[S][4096] x woT[H rows][4096] -> d_out f32 ----------------
__global__ __launch_bounds__(512, 2) void gemm_out_kernel(const unsigned short* __restrict__ A,
                                                          const unsigned short* __restrict__ Bt,
                                                          float* __restrict__ C) {
  extern __shared__ char lds[];
  int bid = blockIdx.x;                 // 224 blocks
  bid = (bid & 7) * 28 + (bid >> 3);
  const int bx = bid & 15, by = bid >> 4;
  const int row0 = bx * 256, col0 = by * 256;
  f32x4 acc[8][4];
  f32x4 z = {0.f, 0.f, 0.f, 0.f};
#pragma unroll
  for (int m = 0; m < 8; ++m)
#pragma unroll
    for (int n = 0; n < 4; ++n) acc[m][n] = z;

  gemm256_mainloop(A, Bt, NQ * D, NQ * D, NQ * D, row0, col0, lds, acc);

  const int lane = threadIdx.x & 63, w = threadIdx.x >> 6;
  const int wm = w >> 2, wn = w & 3;
  const int rbase = row0 + wm * 128 + (lane >> 4) * 4;
  const int cbase = col0 + wn * 64 + (lane & 15);
#pragma unroll
  for (int m = 0; m < 8; ++m)
#pragma unroll
    for (int n = 0; n < 4; ++n)
#pragma unroll
      for (int r = 0; r < 4; ++r)
        C[(size_t)(rbase + m * 16 + r) * H + cbase + n * 16] = acc[m][n][r];
}

// ---------------- flash attention: K/V/P in LDS, 2-exp softcap, Q-RoPE in prologue ----------------
// grid (S/128, NQ), 256 threads = 4 waves; wave w owns 32 q (2 subtiles of 16).
__global__ __launch_bounds__(256, 2) void attn_kernel(const unsigned short* __restrict__ q,
                                                      const unsigned short* __restrict__ kk_,
                                                      const unsigned short* __restrict__ vt,
                                                      const float* __restrict__ cs,
                                                      unsigned short* __restrict__ aout) {
  __shared__ __align__(16) char kl[2][16384];  // K tile [32 keys][256 d] bf16, swizzled
  __shared__ __align__(16) char vl[2][16384];  // Vt tile [256 d][32 keys] bf16, swizzled
  __shared__ __align__(16) char pl[8192];      // P per wave [32 q][32 keys] bf16, swizzled
  const int tid = threadIdx.x, lane = tid & 63, w = tid >> 6;
  const int h = blockIdx.y, hv = h >> 1;    // N_REP = 2
  const int q0 = blockIdx.x * 128;
  const int ql = lane & 15;
  const int grp = lane >> 4;
  const int qw = q0 + w * 32;               // wave q base

  // hoist Q fragments + apply RoPE in-register (partner of qf[t][j] is qf[t^4][j])
  bf16x8 qf[2][8];
#pragma unroll
  for (int qs = 0; qs < 2; ++qs) {
    const int row = qw + qs * 16 + ql;
    const unsigned short* qrow = q + ((size_t)h * S + row) * D;
#pragma unroll
    for (int t = 0; t < 8; ++t)
      qf[qs][t] = *(const bf16x8*)(qrow + t * 32 + grp * 8);
    const float* crow = cs + ((size_t)row << 7);
    const float* srow = crow + (size_t)S * 128;
#pragma unroll
    for (int t = 0; t < 4; ++t)
#pragma unroll
      for (int j = 0; j < 8; ++j) {
        const int dm = t * 32 + grp * 8 + j;
        const float c = crow[dm], s = srow[dm];
        const float lo = bf2f((unsigned short)qf[qs][t][j]);
        const float hi = bf2f((unsigned short)qf[qs][t + 4][j]);
        qf[qs][t][j]     = (short)f2bf(lo * c - hi * s);
        qf[qs][t + 4][j] = (short)f2bf(hi * c + lo * s);
      }
  }

  f32x4 oacc[2][16];
  f32x4 z = {0.f, 0.f, 0.f, 0.f};
#pragma unroll
  for (int qs = 0; qs < 2; ++qs)
#pragma unroll
    for (int i = 0; i < 16; ++i) oacc[qs][i] = z;
  float lrun[2] = {0.0f, 0.0f};

  int lo = q0 - (WINDOW - 1); if (lo < 0) lo = 0;
  const int kb0 = lo & ~31;
  const int kend = q0 + 96;

  const unsigned short* kbase = kk_ + (size_t)hv * S * D;
  const unsigned short* vbase = vt + (size_t)hv * D * S;
  int koff[4], voff[4];
#pragma unroll
  for (int j = 0; j < 4; ++j) {
    int c = w + 4 * j;
    int key = c * 2 + (lane >> 5);
    int colK = (((lane & 31) * 16) ^ ((key & 7) << 4)) >> 1;
    koff[j] = key * D + colK;
    int dd = c * 16 + (lane >> 2);
    int colV = (((lane & 3) * 16) ^ (((dd >> 1) & 3) << 4)) >> 1;
    voff[j] = dd * S + colV;
  }

  auto stage = [&](int buf, int kb) {
#pragma unroll
    for (int j = 0; j < 4; ++j) {
      int c = w + 4 * j;
      load_lds16(kbase + (size_t)kb * D + koff[j], &kl[buf][c * 1024]);
      load_lds16(vbase + kb + voff[j], &vl[buf][c * 1024]);
    }
  };

  stage(0, kb0);
  int cur = 0;
  const int psw = ((ql >> 1) & 3) << 4;
  char* pw = pl + w * 2048;
  const int ksw = (ql & 7) << 4;

  for (int kb = kb0; kb <= kend; kb += 32) {
    __syncthreads();
    if (kb + 32 <= kend) stage(cur ^ 1, kb + 32);

    // scores^T = K(32x256) x Q^T(256x32): A-frag (K) reused across both q-subs
    f32x4 sacc[2][2];
    sacc[0][0] = z; sacc[0][1] = z; sacc[1][0] = z; sacc[1][1] = z;
#pragma unroll
    for (int t = 0; t < 8; ++t) {
      bf16x8 af[2];
#pragma unroll
      for (int ms = 0; ms < 2; ++ms)
        af[ms] = *(const bf16x8*)(kl[cur] + (ms * 16 + ql) * 512 + ((t * 64 + grp * 16) ^ ksw));
      __builtin_amdgcn_s_setprio(1);
#pragma unroll
      for (int qs = 0; qs < 2; ++qs)
#pragma unroll
        for (int ms = 0; ms < 2; ++ms)
          sacc[qs][ms] = __builtin_amdgcn_mfma_f32_16x16x32_bf16(af[ms], qf[qs][t], sacc[qs][ms], 0, 0, 0);
      __builtin_amdgcn_s_setprio(0);
    }

    // fused softcap+softmax vs fixed max 50: p = exp(-100 / (exp(x*SCALE/25) + 1))
#pragma unroll
    for (int qs = 0; qs < 2; ++qs) {
      const int qsb = qw + qs * 16;
      const int qg = qsb + ql;
      float pv[8];
#pragma unroll
      for (int i = 0; i < 8; ++i) {
        float x = sacc[qs][i >> 2][i & 3];
        float e = __expf(x * (SCALE / 25.0f));
        float rc = __builtin_amdgcn_rcpf(e + 1.0f);
        pv[i] = __expf(rc * -100.0f);
      }
      if (kb + 31 > qsb) {                 // causal edge
#pragma unroll
        for (int i = 0; i < 8; ++i) {
          int key = kb + (i >> 2) * 16 + grp * 4 + (i & 3);
          if (key > qg) pv[i] = 0.0f;
        }
      } else if (kb < qsb - 2032) {        // window edge
#pragma unroll
        for (int i = 0; i < 8; ++i) {
          int key = kb + (i >> 2) * 16 + grp * 4 + (i & 3);
          if (key <= qg - WINDOW) pv[i] = 0.0f;
        }
      }
#pragma unroll
      for (int i = 0; i < 8; ++i) lrun[qs] += pv[i];

#pragma unroll
      for (int ms = 0; ms < 2; ++ms) {
        short4v pk;
        pk[0] = (short)f2bf(pv[ms * 4 + 0]);
        pk[1] = (short)f2bf(pv[ms * 4 + 1]);
        pk[2] = (short)f2bf(pv[ms * 4 + 2]);
        pk[3] = (short)f2bf(pv[ms * 4 + 3]);
        *(short4v*)(pw + (qs * 16 + ql) * 64 + ((ms * 32 + grp * 8) ^ psw)) = pk;
      }
    }
    asm volatile("s_waitcnt lgkmcnt(0)" ::: "memory");
    bf16x8 pb[2];
#pragma unroll
    for (int qs = 0; qs < 2; ++qs)
      pb[qs] = *(const bf16x8*)(pw + (qs * 16 + ql) * 64 + ((grp * 16) ^ psw));

    // O^T += Vt(256x32) x P^T(32x32): V A-frag reused across both q-subs
#pragma unroll
    for (int nt = 0; nt < 16; ++nt) {
      int dr = nt * 16 + ql;
      bf16x8 va = *(const bf16x8*)(vl[cur] + dr * 64 + ((grp * 16) ^ (((dr >> 1) & 3) << 4)));
      __builtin_amdgcn_s_setprio(1);
      oacc[0][nt] = __builtin_amdgcn_mfma_f32_16x16x32_bf16(va, pb[0], oacc[0][nt], 0, 0, 0);
      oacc[1][nt] = __builtin_amdgcn_mfma_f32_16x16x32_bf16(va, pb[1], oacc[1][nt], 0, 0, 0);
      __builtin_amdgcn_s_setprio(0);
    }
    cur ^= 1;
  }

  // epilogue: reduce l across the 4 lane-groups (same q col), normalize, store
#pragma unroll
  for (int qs = 0; qs < 2; ++qs) {
    float l = lrun[qs];
    l += __shfl_xor(l, 16);
    l += __shfl_xor(l, 32);
    l = fmaxf(l, 1e-35f);
    float rl = 1.0f / l;
    unsigned short* orow = aout + (size_t)(qw + qs * 16 + ql) * (NQ * D) + h * D;
#pragma unroll
    for (int nt = 0; nt < 16; ++nt) {
      short4v o;
      o[0] = (short)f2bf(oacc[qs][nt][0] * rl);
      o[1] = (short)f2bf(oacc[qs][nt][1] * rl);
      o[2] = (short)f2bf(oacc[qs][nt][2] * rl);
      o[3] = (short)f2bf(oacc[qs][nt][3] * rl);
      *(short4v*)(orow + nt * 16 + grp * 4) = o;
    }
  }
}

// ---------------- launch ----------------
extern "C" void kernel_launch(void* const* d_in, const int* in_sizes, int n_in,
                              void* d_out, int out_size, void* d_ws, size_t ws_size,
                              hipStream_t stream) {
  const float* hs = (const float*)d_in[0];
  const float* wq = (const float*)d_in[1];
  const float* wk = (const float*)d_in[2];
  const float* wv = (const float*)d_in[3];
  const float* wo = (const float*)d_in[4];
  float* out = (float*)d_out;

  char* ws = (char*)d_ws;
  size_t off = 0;
  auto alloc = [&](size_t bytes) {
    char* p = ws + off;
    off += (bytes + 255) & ~(size_t)255;
    return p;
  };
  unsigned short* hsb   = (unsigned short*)alloc((size_t)S * H * 2);
  unsigned short* wqkvT = (unsigned short*)alloc((size_t)8192 * H * 2);
  unsigned short* woT   = (unsigned short*)alloc((size_t)H * 4096 * 2);
  unsigned short* qb    = (unsigned short*)alloc((size_t)NQ * S * D * 2);
  unsigned short* kbuf  = (unsigned short*)alloc((size_t)NKV * S * D * 2);
  unsigned short* vtb   = (unsigned short*)alloc((size_t)NKV * D * S * 2);
  unsigned short* aob   = (unsigned short*)alloc((size_t)S * NQ * D * 2);
  float*          cs    = (float*)alloc((size_t)S * 128 * 2 * 4);
  if (off > ws_size) return;

  cast_hs_kernel<<<(S * H) / 2048, 256, 0, stream>>>(hs, hsb);
  transpose_cast_kernel<<<dim3(4096 / 64, H / 64), 256, 0, stream>>>(wq, wqkvT, H, 4096, H);
  transpose_cast_kernel<<<dim3(2048 / 64, H / 64), 256, 0, stream>>>(wk, wqkvT + (size_t)4096 * H, H, 2048, H);
  transpose_cast_kernel<<<dim3(2048 / 64, H / 64), 256, 0, stream>>>(wv, wqkvT + (size_t)6144 * H, H, 2048, H);
  transpose_cast_kernel<<<dim3(H / 64, 4096 / 64), 256, 0, stream>>>(wo, woT, 4096, H, 4096);
  rope_table_kernel<<<(S * 128) / 256, 256, 0, stream>>>(cs);
  gemm_qkv_kernel<<<512, 512, 131072, stream>>>(hsb, wqkvT, qb, kbuf, vtb);
  rope_apply_k_kernel<<<(NKV * S * 32) / 256, 256, 0, stream>>>(kbuf, cs);
  attn_kernel<<<dim3(S / 128, NQ), 256, 0, stream>>>(qb, kbuf, vtb, cs, aob);
  gemm_out_kernel<<<224, 512, 131072, stream>>>(aob, woT, out);
}